// Round 2
// baseline (322.563 us; speedup 1.0000x reference)
//
#include <hip/hip_runtime.h>

// SpinorBilinears: K0 = psi.psi; T'[c][d] = (0.5 psi)^T gamma_c gamma_d psi
// K1 = T' - T'^T, K2 = T' + T'^T. Tokens = B*N = 524288, S=4, C=8.
// Output f32 concat: K0 [T] | K1 [T,8,8] | K2 [T,8,8]  (~270 MB -> write-bound).
//
// Design: one thread per token; full T in registers (transpose is thread-local).
// Wave-private LDS chunk staging (stride 17 -> <=2-way banks, free) turns
// per-thread 64-float rows into fully coalesced 64B-aligned float4 streams.
// No __syncthreads: per-wave DS ops are in-order; wave_barrier pins the compiler.

#define TPB 256
#define STG 17   // floats per token row in staging (16 + 1): 2-way banks max

__device__ __forceinline__ float dot4(float4 a, float4 b) {
    return a.x * b.x + a.y * b.y + a.z * b.z + a.w * b.w;
}

__global__ __launch_bounds__(TPB, 4) void spinor_bilinears_kernel(
    const float* __restrict__ psi,
    const float* __restrict__ gamma,
    float* __restrict__ out,
    int n_tokens) {
    __shared__ float stgA[4][64 * STG];   // per-wave K1 staging
    __shared__ float stgB[4][64 * STG];   // per-wave K2 staging

    const int tid  = threadIdx.x;
    const int wave = tid >> 6;
    const int lane = tid & 63;
    const int g0   = blockIdx.x * TPB + (wave << 6);  // wave's first token
    const int g    = g0 + lane;                       // this thread's token

    float*  K0  = out;
    float4* K1v = (float4*)(out + n_tokens);
    float4* K2v = (float4*)(out + n_tokens + (size_t)n_tokens * 64);

    // ---- per-token compute, all in registers ----
    const float4 p = ((const float4*)psi)[g];
    K0[g] = dot4(p, p);                                // coalesced 256B/wave
    const float4 ph = make_float4(0.5f * p.x, 0.5f * p.y, 0.5f * p.z, 0.5f * p.w);

    // u[c] = (0.5 psi)^T gamma_c ; v[c] = gamma_c psi   (gamma is wave-uniform
    // -> compiler lifts to s_load; ~32 SGPRs)
    float4 u[8], v[8];
    const float4* g4 = (const float4*)gamma;
#pragma unroll
    for (int c = 0; c < 8; ++c) {
        const float4 r0 = g4[c * 4 + 0];
        const float4 r1 = g4[c * 4 + 1];
        const float4 r2 = g4[c * 4 + 2];
        const float4 r3 = g4[c * 4 + 3];
        u[c] = make_float4(ph.x * r0.x + ph.y * r1.x + ph.z * r2.x + ph.w * r3.x,
                           ph.x * r0.y + ph.y * r1.y + ph.z * r2.y + ph.w * r3.y,
                           ph.x * r0.z + ph.y * r1.z + ph.z * r2.z + ph.w * r3.z,
                           ph.x * r0.w + ph.y * r1.w + ph.z * r2.w + ph.w * r3.w);
        v[c] = make_float4(dot4(r0, p), dot4(r1, p), dot4(r2, p), dot4(r3, p));
    }

    float T[8][8];  // T' = 0.5 * psi^T gamma_c gamma_d psi
#pragma unroll
    for (int c = 0; c < 8; ++c)
#pragma unroll
        for (int d = 0; d < 8; ++d)
            T[c][d] = dot4(u[c], v[d]);

    float* A = &stgA[wave][0];
    float* B = &stgB[wave][0];

    // ---- chunked staging: 4 chunks of 16 floats (rows c=2k,2k+1) ----
#pragma unroll
    for (int k = 0; k < 4; ++k) {
        // scalar writes at stride-17 rows: bank = lane + 16*(lane&1) + f -> 2-way max
#pragma unroll
        for (int f = 0; f < 16; ++f) {
            const int c = 2 * k + (f >> 3);
            const int d = f & 7;
            A[lane * STG + f] = T[c][d] - T[d][c];
            B[lane * STG + f] = T[c][d] + T[d][c];
        }
        __builtin_amdgcn_s_waitcnt(0xC07F);   // lgkmcnt(0) only (vm=63, exp=7)
        __builtin_amdgcn_wave_barrier();

        // cooperative readback + coalesced stores: each wave-store = 16 full
        // 64B-aligned lines (16 tokens x chunk k), stride 256B between groups
#pragma unroll
        for (int s = 0; s < 4; ++s) {
            const int trow = (s << 4) + (lane >> 2);
            const int rb   = trow * STG + (lane & 3) * 4;
            const float4 av = make_float4(A[rb], A[rb + 1], A[rb + 2], A[rb + 3]);
            const float4 bv = make_float4(B[rb], B[rb + 1], B[rb + 2], B[rb + 3]);
            const int f4i = ((g0 + trow) << 4) + (k << 2) + (lane & 3);
            K1v[f4i] = av;
            K2v[f4i] = bv;
        }
        __builtin_amdgcn_wave_barrier();      // keep next chunk's writes behind reads
    }
}

extern "C" void kernel_launch(void* const* d_in, const int* in_sizes, int n_in,
                              void* d_out, int out_size, void* d_ws, size_t ws_size,
                              hipStream_t stream) {
    const float* psi = (const float*)d_in[0];
    const float* gamma = (const float*)d_in[1];
    float* out = (float*)d_out;

    const int n_tokens = in_sizes[0] / 4;        // B*N = 524288
    const int blocks = n_tokens / TPB;           // 2048

    spinor_bilinears_kernel<<<blocks, TPB, 0, stream>>>(psi, gamma, out, n_tokens);
}

// Round 4
// 280.357 us; speedup vs baseline: 1.1505x; 1.1505x over previous
//
#include <hip/hip_runtime.h>

// SpinorBilinears: K0 = psi.psi; T'[c][d] = (0.5 psi)^T gamma_c gamma_d psi
// K1 = T' - T'^T, K2 = T' + T'^T. Tokens = B*N = 524288, S=4, C=8.
// Output f32 concat: K0 [T] | K1 [T,8,8] | K2 [T,8,8]  (~270 MB, write-once).
//
// R4 = R3 with native clang vector type for nontemporal builtins
// (HIP float4 is a struct -> rejected by __builtin_nontemporal_*).
//
//  - NON-TEMPORAL stores everywhere: outputs never re-read; avoids L2
//    read-for-ownership (suspected 2x tax: ~98us measured vs 44us roofline).
//  - Transpose is thread-local: K1/K2 values computed in registers; LDS used
//    only as a float4 lane-shuffle. Layout [chunk][token] -> every b128
//    write/read spreads 8 lanes per bank-quad (conflict-free, ~12 cyc).
//  - 4 wave-private sub-passes (K1 lo/hi, K2 lo/hi), wave_barrier only,
//    no __syncthreads. 32KB LDS, __launch_bounds__(256,4) -> 16 waves/CU.

#define TPB 256

typedef float v4f __attribute__((ext_vector_type(4)));

__device__ __forceinline__ float dot4(v4f a, v4f b) {
    return a.x * b.x + a.y * b.y + a.z * b.z + a.w * b.w;
}

__global__ __launch_bounds__(TPB, 4) void spinor_bilinears_kernel(
    const float* __restrict__ psi,
    const float* __restrict__ gamma,
    float* __restrict__ out,
    int n_tokens) {
    __shared__ v4f stg[4][8][64];   // [wave][chunk][token] = 32 KB

    const int tid  = threadIdx.x;
    const int wave = tid >> 6;
    const int lane = tid & 63;
    const int g0w  = blockIdx.x * TPB + (wave << 6);  // wave's first token
    const int g    = g0w + lane;                      // this thread's token

    float* K0  = out;
    v4f*   K1v = (v4f*)(out + n_tokens);
    v4f*   K2v = (v4f*)(out + n_tokens + (size_t)n_tokens * 64);

    // ---- per-token compute, all in registers ----
    const v4f p = __builtin_nontemporal_load(&((const v4f*)psi)[g]);
    __builtin_nontemporal_store(dot4(p, p), &K0[g]);  // coalesced 256B/wave
    const v4f ph = p * 0.5f;

    const v4f* g4 = (const v4f*)gamma;  // wave-uniform -> scalar loads

    // v[c] = gamma_c psi  (keep only v live while building T: modest VGPR)
    v4f v[8];
#pragma unroll
    for (int c = 0; c < 8; ++c) {
        const v4f r0 = g4[c * 4 + 0];
        const v4f r1 = g4[c * 4 + 1];
        const v4f r2 = g4[c * 4 + 2];
        const v4f r3 = g4[c * 4 + 3];
        v4f vc;
        vc.x = dot4(r0, p);
        vc.y = dot4(r1, p);
        vc.z = dot4(r2, p);
        vc.w = dot4(r3, p);
        v[c] = vc;
    }

    // T'[c][d] = dot(u_c, v_d), u_c = (0.5 psi)^T gamma_c  (u_c transient)
    float T[8][8];
#pragma unroll
    for (int c = 0; c < 8; ++c) {
        const v4f r0 = g4[c * 4 + 0];
        const v4f r1 = g4[c * 4 + 1];
        const v4f r2 = g4[c * 4 + 2];
        const v4f r3 = g4[c * 4 + 3];
        const v4f uc = ph.x * r0 + ph.y * r1 + ph.z * r2 + ph.w * r3;
#pragma unroll
        for (int d = 0; d < 8; ++d) T[c][d] = dot4(uc, v[d]);
    }

    v4f (*S)[64] = stg[wave];
    const int qr  = lane & 7;    // readback chunk
    const int tr0 = lane >> 3;   // readback token base

    // ---- 4 wave-private sub-passes: K1 lo/hi, K2 lo/hi ----
#pragma unroll
    for (int pass = 0; pass < 4; ++pass) {
        const int   c0   = (pass & 1) * 4;
        const int   q0   = (pass & 1) * 8;
        const float sgn  = (pass < 2) ? -1.0f : 1.0f;
        v4f*        base = (pass < 2) ? K1v : K2v;

        // stage: thread 'lane' writes its 8 chunks (b128, conflict-free)
#pragma unroll
        for (int q = 0; q < 8; ++q) {
            const int c  = c0 + (q >> 1);
            const int d0 = (q & 1) * 4;
            v4f val;
            val.x = T[c][d0 + 0] + sgn * T[d0 + 0][c];
            val.y = T[c][d0 + 1] + sgn * T[d0 + 1][c];
            val.z = T[c][d0 + 2] + sgn * T[d0 + 2][c];
            val.w = T[c][d0 + 3] + sgn * T[d0 + 3][c];
            S[q][lane] = val;
        }
        __builtin_amdgcn_s_waitcnt(0xC07F);   // lgkmcnt(0) only
        __builtin_amdgcn_wave_barrier();

        // readback + NT store: each instr = 8 aligned 128B runs (16 full lines)
#pragma unroll
        for (int s = 0; s < 8; ++s) {
            const int t = (s << 3) + tr0;
            const v4f vv = S[qr][t];
            __builtin_nontemporal_store(
                vv, &base[(size_t)(g0w + t) * 16 + q0 + qr]);
        }
        __builtin_amdgcn_wave_barrier();      // keep next pass's writes behind reads
    }
}

extern "C" void kernel_launch(void* const* d_in, const int* in_sizes, int n_in,
                              void* d_out, int out_size, void* d_ws, size_t ws_size,
                              hipStream_t stream) {
    const float* psi = (const float*)d_in[0];
    const float* gamma = (const float*)d_in[1];
    float* out = (float*)d_out;

    const int n_tokens = in_sizes[0] / 4;   // B*N = 524288
    const int blocks = n_tokens / TPB;      // 2048

    spinor_bilinears_kernel<<<blocks, TPB, 0, stream>>>(psi, gamma, out, n_tokens);
}